// Round 4
// baseline (209.492 us; speedup 1.0000x reference)
//
#include <hip/hip_runtime.h>
#include <math.h>

#define NV 778
#define KROW 2334     // NV*3
#define KTOT 146      // 10 beta + 135 pose-feature + 1 const(template)
#define NCOL 1008     // 21 j * 16 jj * 3 c
#define NPART 8       // v-splits in precompute
#define VSP 98        // ceil(778/NPART)
#define WPAD 99       // LDS tile row stride (99: lane-stride 3 mod 32 -> 2-way alias, free)

// ======================= kA: batch-independent precompute ====================
// bid <  48  : SJ[k][j][c], J0[j][c]   (chain joint regressors, j<16)
// bid <  384 : Q[j*16+jj] = sum_v Jreg[v][j]*wgt[v][jj]
// else       : W2[v][j*16+jj] = Jreg[v][j]*wgt[v][jj]
__global__ __launch_bounds__(64) void kA_pre(const float* __restrict__ shapedirs,
                                             const float* __restrict__ v_template,
                                             const float* __restrict__ Jreg,
                                             const float* __restrict__ wgt,
                                             float* __restrict__ SJ, float* __restrict__ J0,
                                             float* __restrict__ Q,  float* __restrict__ W2)
{
    const int bid = blockIdx.x;
    const int t = threadIdx.x;
    if (bid < 48) {
        const int j = bid / 3, c = bid % 3;
        float acc[11];
#pragma unroll
        for (int k = 0; k < 11; ++k) acc[k] = 0.f;
        for (int v = t; v < NV; v += 64) {
            const float jr = Jreg[v*21 + j];
            acc[10] += v_template[v*3 + c] * jr;
#pragma unroll
            for (int k = 0; k < 10; ++k)
                acc[k] += shapedirs[(size_t)k*KROW + v*3 + c] * jr;
        }
#pragma unroll
        for (int k = 0; k < 11; ++k) {
            float s = acc[k];
#pragma unroll
            for (int off = 32; off >= 1; off >>= 1) s += __shfl_down(s, off, 64);
            acc[k] = s;
        }
        if (t == 0) {
#pragma unroll
            for (int k = 0; k < 10; ++k) SJ[k*48 + j*3 + c] = acc[k];
            J0[j*3 + c] = acc[10];
        }
    } else if (bid < 384) {
        const int m = bid - 48, j = m >> 4, jj = m & 15;
        float s = 0.f;
        for (int v = t; v < NV; v += 64)
            s += Jreg[v*21 + j] * wgt[v*16 + jj];
#pragma unroll
        for (int off = 32; off >= 1; off >>= 1) s += __shfl_down(s, off, 64);
        if (t == 0) Q[m] = s;
    } else {
        const int gi = (bid - 384)*64 + t;
        if (gi < NV*336) {
            const int v = gi / 336, m = gi % 336;
            const int j = m >> 4, jj = m & 15;
            W2[gi] = Jreg[v*21 + j] * wgt[v*16 + jj];
        }
    }
}

// ======================= k_pre2: PK partials (batch-independent) =============
// block = (j, c, s). LDS-staged dirs c-slice so the v-loop is conflict-free LDS
// + uniform s_load of the W2 row + 16 FMA. Output stored c-major-16 within the
// j-group: PKpart[s][k][j*48 + c*16 + jj]  (one 64B line per thread).
__global__ __launch_bounds__(192) void k_pre2(const float* __restrict__ shapedirs,
                                              const float* __restrict__ posedirs,
                                              const float* __restrict__ v_template,
                                              const float* __restrict__ W2,
                                              float* __restrict__ PKpart)
{
    __shared__ float tile[KTOT*WPAD];
    const int bid = blockIdx.x;          // 21*3*NPART
    const int j = bid % 21;
    const int c = (bid / 21) % 3;
    const int s = bid / 63;
    const int v0 = s*VSP;
    const int nv = min(VSP, NV - v0);
    const int t = threadIdx.x;

    for (int idx = t; idx < KTOT*VSP; idx += 192) {
        const int k = idx / VSP;
        const int xx = idx - k*VSP;
        if (xx < nv) {
            const float* drow = (k < 10)  ? shapedirs + (size_t)k*KROW
                              : (k < 145) ? posedirs + (size_t)(k-10)*KROW
                                          : v_template;
            tile[k*WPAD + xx] = drow[3*(v0+xx) + c];
        }
    }
    __syncthreads();

    if (t < KTOT) {
        float acc[16];
#pragma unroll
        for (int q = 0; q < 16; ++q) acc[q] = 0.f;
        const float* tr = tile + t*WPAD;
        for (int vv = 0; vv < nv; ++vv) {
            const float d = tr[vv];
            const float4* wq = (const float4*)(W2 + (size_t)(v0+vv)*336 + j*16);  // uniform
            const float4 w0 = wq[0], w1 = wq[1], w2 = wq[2], w3 = wq[3];
            acc[0]  += d*w0.x; acc[1]  += d*w0.y; acc[2]  += d*w0.z; acc[3]  += d*w0.w;
            acc[4]  += d*w1.x; acc[5]  += d*w1.y; acc[6]  += d*w1.z; acc[7]  += d*w1.w;
            acc[8]  += d*w2.x; acc[9]  += d*w2.y; acc[10] += d*w2.z; acc[11] += d*w2.w;
            acc[12] += d*w3.x; acc[13] += d*w3.y; acc[14] += d*w3.z; acc[15] += d*w3.w;
        }
        float4* o = (float4*)(PKpart + ((size_t)s*KTOT + t)*NCOL + j*48 + c*16);
        o[0] = make_float4(acc[0],  acc[1],  acc[2],  acc[3]);
        o[1] = make_float4(acc[4],  acc[5],  acc[6],  acc[7]);
        o[2] = make_float4(acc[8],  acc[9],  acc[10], acc[11]);
        o[3] = make_float4(acc[12], acc[13], acc[14], acc[15]);
    }
}

// ======================= k_p3: reduce partials -> PK[146][1008] ==============
// Also un-permutes (c-major-16 -> jj*3+c).
__global__ void k_p3(const float* __restrict__ PKpart, float* __restrict__ PK)
{
    const int idx = blockIdx.x*256 + threadIdx.x;
    if (idx < KTOT*NCOL) {
        const int k = idx / NCOL, n = idx - k*NCOL;
        const int j = n / 48, r = n - j*48;
        const int jj = r / 3, c = r - jj*3;
        const size_t src = (size_t)k*NCOL + j*48 + c*16 + jj;
        float acc = 0.f;
#pragma unroll
        for (int s = 0; s < NPART; ++s)
            acc += PKpart[(size_t)s*KTOT*NCOL + src];
        PK[idx] = acc;
    }
}

// ======================= k2: rodrigues + coefT + kinematic chain =============
// block = 16 batches x 16 joints. Writes coefT[k][B] (k<146, row 145 = 1.0) and A_g[b][192].
__global__ __launch_bounds__(256) void k2_pose(const float* __restrict__ beta,
                                               const float* __restrict__ theta,
                                               const float* __restrict__ wrist,
                                               const float* __restrict__ hc,
                                               const float* __restrict__ hm,
                                               const float* __restrict__ SJ,
                                               const float* __restrict__ J0,
                                               float* __restrict__ coefT,
                                               float* __restrict__ A_g, int B)
{
    __shared__ float Rs[16*144];    // [b_loc][i*9+q]
    __shared__ float cls[16*148];   // [b_loc][k]
    const int t = threadIdx.x;
    const int bl = t >> 4, i = t & 15;
    const int b = blockIdx.x*16 + bl;

    float r0, r1, r2;
    if (i == 0) {
        r0 = wrist[b*3+0]; r1 = wrist[b*3+1]; r2 = wrist[b*3+2];
#pragma unroll
        for (int k = 0; k < 10; ++k) cls[bl*148 + k] = beta[b*10 + k];
        cls[bl*148 + 145] = 1.0f;
    } else {
        const int col = (i-1)*3;
        float e0 = hm[col], e1 = hm[col+1], e2 = hm[col+2];
#pragma unroll
        for (int k = 0; k < 10; ++k) {
            const float th = theta[b*10 + k];
            e0 += th * hc[k*45 + col];
            e1 += th * hc[k*45 + col+1];
            e2 += th * hc[k*45 + col+2];
        }
        r0 = e0; r1 = e1; r2 = e2;
    }
    // rodrigues (matches reference: eps added per-component before norm; axis uses raw r)
    const float x_ = r0 + 1e-8f, y_ = r1 + 1e-8f, z_ = r2 + 1e-8f;
    const float angle = sqrtf(x_*x_ + y_*y_ + z_*z_);
    const float inv = 1.0f / angle;
    const float x = r0*inv, y = r1*inv, z = r2*inv;
    const float sn = sinf(angle), cs = cosf(angle);
    const float t1 = 1.0f - cs;
    float R[9];
    R[0] = 1.f - t1*(y*y + z*z);
    R[1] = -sn*z + t1*x*y;
    R[2] =  sn*y + t1*x*z;
    R[3] =  sn*z + t1*x*y;
    R[4] = 1.f - t1*(x*x + z*z);
    R[5] = -sn*x + t1*y*z;
    R[6] = -sn*y + t1*x*z;
    R[7] =  sn*x + t1*y*z;
    R[8] = 1.f - t1*(x*x + y*y);
#pragma unroll
    for (int q = 0; q < 9; ++q) Rs[bl*144 + i*9 + q] = R[q];
    if (i > 0) {
#pragma unroll
        for (int q = 0; q < 9; ++q)
            cls[bl*148 + 10 + (i-1)*9 + q] = R[q] - ((q==0||q==4||q==8) ? 1.f : 0.f);
    }
    __syncthreads();

    // transposed coefT store: row t, 16 batch columns
    if (t < KTOT) {
        float tmp[16];
#pragma unroll
        for (int m = 0; m < 16; ++m) tmp[m] = cls[m*148 + t];
        float4* dst = (float4*)(coefT + (size_t)t*B + blockIdx.x*16);
        dst[0] = make_float4(tmp[0],  tmp[1],  tmp[2],  tmp[3]);
        dst[1] = make_float4(tmp[4],  tmp[5],  tmp[6],  tmp[7]);
        dst[2] = make_float4(tmp[8],  tmp[9],  tmp[10], tmp[11]);
        dst[3] = make_float4(tmp[12], tmp[13], tmp[14], tmp[15]);
    }

    // kinematic chain: one thread per batch (t<16)
    if (t < 16) {
        const int b2 = blockIdx.x*16 + t;
        float bt[10];
#pragma unroll
        for (int k = 0; k < 10; ++k) bt[k] = beta[b2*10 + k];
        const float* Rb = Rs + t*144;
        float4* Ab = (float4*)(A_g + (size_t)b2*192);

        auto jointJ = [&](int j, float* o) {
            float j0 = J0[j*3+0], j1 = J0[j*3+1], j2 = J0[j*3+2];
#pragma unroll
            for (int k = 0; k < 10; ++k) {
                j0 += bt[k] * SJ[k*48 + j*3 + 0];
                j1 += bt[k] * SJ[k*48 + j*3 + 1];
                j2 += bt[k] * SJ[k*48 + j*3 + 2];
            }
            o[0] = j0; o[1] = j1; o[2] = j2;
        };

        float G0R[9], J0v[3];
#pragma unroll
        for (int q = 0; q < 9; ++q) G0R[q] = Rb[q];
        jointJ(0, J0v);
#pragma unroll
        for (int r = 0; r < 3; ++r) {
            const float at = J0v[r] - (G0R[r*3+0]*J0v[0] + G0R[r*3+1]*J0v[1] + G0R[r*3+2]*J0v[2]);
            Ab[r] = make_float4(G0R[r*3+0], G0R[r*3+1], G0R[r*3+2], at);
        }
        for (int ch = 0; ch < 5; ++ch) {
            float GpR[9], Gpt[3], Jp[3];
#pragma unroll
            for (int q = 0; q < 9; ++q) GpR[q] = G0R[q];
            Gpt[0]=J0v[0]; Gpt[1]=J0v[1]; Gpt[2]=J0v[2];
            Jp[0]=J0v[0];  Jp[1]=J0v[1];  Jp[2]=J0v[2];
            for (int s = 0; s < 3; ++s) {
                const int j = ch*3 + 1 + s;
                float Rl[9];
                const float* Rj = Rb + j*9;
#pragma unroll
                for (int q = 0; q < 9; ++q) Rl[q] = Rj[q];
                float Jc[3];
                jointJ(j, Jc);
                const float tl0 = Jc[0]-Jp[0], tl1 = Jc[1]-Jp[1], tl2 = Jc[2]-Jp[2];
                float GR[9], Gt[3];
#pragma unroll
                for (int r = 0; r < 3; ++r) {
#pragma unroll
                    for (int cc = 0; cc < 3; ++cc)
                        GR[r*3+cc] = GpR[r*3+0]*Rl[0*3+cc] + GpR[r*3+1]*Rl[1*3+cc] + GpR[r*3+2]*Rl[2*3+cc];
                    Gt[r] = GpR[r*3+0]*tl0 + GpR[r*3+1]*tl1 + GpR[r*3+2]*tl2 + Gpt[r];
                }
#pragma unroll
                for (int r = 0; r < 3; ++r) {
                    const float at = Gt[r] - (GR[r*3+0]*Jc[0] + GR[r*3+1]*Jc[1] + GR[r*3+2]*Jc[2]);
                    Ab[j*3 + r] = make_float4(GR[r*3+0], GR[r*3+1], GR[r*3+2], at);
                }
#pragma unroll
                for (int q = 0; q < 9; ++q) GpR[q] = GR[q];
                Gpt[0]=Gt[0]; Gpt[1]=Gt[1]; Gpt[2]=Gt[2];
                Jp[0]=Jc[0];  Jp[1]=Jc[1];  Jp[2]=Jc[2];
            }
        }
    }
}

// ======================= k3: P-GEMM (B x 1008 x 146) + fused joint epilogue ==
// grid (B/128, 21). PK j-strip (146x48 = 28 KB) staged in LDS once per block;
// K-loop: 3 broadcast ds_read_b128 + 1 coalesced float2 coef load + 24 FMA.
// LDS 53 KB -> 3 blocks/CU (12 waves/CU).
__global__ __launch_bounds__(256) void k3_gemm(const float* __restrict__ coefT,
                                               const float* __restrict__ PK,
                                               const float* __restrict__ A_g,
                                               const float* __restrict__ Q,
                                               float* __restrict__ out, int B)
{
    __shared__ float pks[KTOT*48];
    __shared__ float Pex[128*49];
    const int t  = threadIdx.x;
    const int b0 = blockIdx.x * 128;
    const int j  = blockIdx.y;
    const int ci = t >> 6;
    const int bi = t & 63;

    for (int idx = t; idx < KTOT*48; idx += 256) {
        const int k = idx / 48, xx = idx - k*48;
        pks[idx] = PK[(size_t)k*NCOL + j*48 + xx];
    }
    __syncthreads();

    float acc[3][4][2];
#pragma unroll
    for (int u = 0; u < 3; ++u)
#pragma unroll
        for (int cc = 0; cc < 4; ++cc) { acc[u][cc][0] = 0.f; acc[u][cc][1] = 0.f; }

    const float* cbase = coefT + b0 + 2*bi;    // per-lane, coalesced
    const float* pl    = pks + 4*ci;           // wave-uniform -> LDS broadcast

#pragma unroll 2
    for (int k = 0; k < KTOT; ++k) {
        const float2 c2 = *(const float2*)(cbase + (size_t)k*B);
        const float4 p0 = *(const float4*)(pl + k*48);
        const float4 p1 = *(const float4*)(pl + k*48 + 16);
        const float4 p2 = *(const float4*)(pl + k*48 + 32);
        acc[0][0][0] += p0.x*c2.x; acc[0][0][1] += p0.x*c2.y;
        acc[0][1][0] += p0.y*c2.x; acc[0][1][1] += p0.y*c2.y;
        acc[0][2][0] += p0.z*c2.x; acc[0][2][1] += p0.z*c2.y;
        acc[0][3][0] += p0.w*c2.x; acc[0][3][1] += p0.w*c2.y;
        acc[1][0][0] += p1.x*c2.x; acc[1][0][1] += p1.x*c2.y;
        acc[1][1][0] += p1.y*c2.x; acc[1][1][1] += p1.y*c2.y;
        acc[1][2][0] += p1.z*c2.x; acc[1][2][1] += p1.z*c2.y;
        acc[1][3][0] += p1.w*c2.x; acc[1][3][1] += p1.w*c2.y;
        acc[2][0][0] += p2.x*c2.x; acc[2][0][1] += p2.x*c2.y;
        acc[2][1][0] += p2.y*c2.x; acc[2][1][1] += p2.y*c2.y;
        acc[2][2][0] += p2.z*c2.x; acc[2][2][1] += p2.z*c2.y;
        acc[2][3][0] += p2.w*c2.x; acc[2][3][1] += p2.w*c2.y;
    }

#pragma unroll
    for (int u = 0; u < 3; ++u)
#pragma unroll
        for (int cc = 0; cc < 4; ++cc)
#pragma unroll
            for (int e = 0; e < 2; ++e)
                Pex[(2*bi + e)*49 + 16*u + 4*ci + cc] = acc[u][cc][e];
    __syncthreads();

    if (t < 128) {
        const int b = b0 + t;
        const float4* Ab = ((const float4*)A_g) + (size_t)b*48;
        const float* Pr = Pex + t*49;
        float jx = 0.f, jy = 0.f, jz = 0.f;
#pragma unroll
        for (int jj = 0; jj < 16; ++jj) {
            const float qv = Q[j*16 + jj];              // uniform -> s_load
            const float4 a0 = Ab[jj*3+0];
            const float4 a1 = Ab[jj*3+1];
            const float4 a2 = Ab[jj*3+2];
            const float px = Pr[jj*3+0], py = Pr[jj*3+1], pz = Pr[jj*3+2];
            jx += a0.x*px + a0.y*py + a0.z*pz + a0.w*qv;
            jy += a1.x*px + a1.y*py + a1.z*pz + a1.w*qv;
            jz += a2.x*px + a2.y*py + a2.z*pz + a2.w*qv;
        }
        float* op = out + (size_t)b*63 + j*3;
        op[0] = jx; op[1] = jy; op[2] = jz;
    }
}

// ============================================================================
extern "C" void kernel_launch(void* const* d_in, const int* in_sizes, int n_in,
                              void* d_out, int out_size, void* d_ws, size_t ws_size,
                              hipStream_t stream) {
    (void)n_in; (void)out_size; (void)ws_size;
    const float* beta       = (const float*)d_in[0];
    const float* theta      = (const float*)d_in[1];
    const float* wrist      = (const float*)d_in[2];
    const float* v_template = (const float*)d_in[3];
    const float* shapedirs  = (const float*)d_in[4];
    const float* posedirs   = (const float*)d_in[5];
    const float* Jreg       = (const float*)d_in[6];
    const float* hc         = (const float*)d_in[7];
    const float* hm         = (const float*)d_in[8];
    const float* wgt        = (const float*)d_in[9];
    float* out = (float*)d_out;
    const int B = in_sizes[0] / 10;

    float* ws = (float*)d_ws;
    size_t off = 0;
    auto alloc = [&](size_t n) { float* p = ws + off; off = (off + n + 63) & ~(size_t)63; return p; };
    float* SJ     = alloc(480);
    float* J0     = alloc(48);
    float* Q      = alloc(336);
    float* W2     = alloc((size_t)NV*336);
    float* PKpart = alloc((size_t)NPART*KTOT*NCOL);
    float* PK     = alloc((size_t)KTOT*NCOL);
    float* coefT  = alloc((size_t)KTOT*B);
    float* A_g    = alloc((size_t)B*192);

    const int w2_blocks = (NV*336 + 63)/64;
    kA_pre<<<384 + w2_blocks, 64, 0, stream>>>(shapedirs, v_template, Jreg, wgt, SJ, J0, Q, W2);
    k2_pose<<<(B + 15)/16, 256, 0, stream>>>(beta, theta, wrist, hc, hm, SJ, J0, coefT, A_g, B);
    k_pre2<<<21*3*NPART, 192, 0, stream>>>(shapedirs, posedirs, v_template, W2, PKpart);
    k_p3<<<(KTOT*NCOL + 255)/256, 256, 0, stream>>>(PKpart, PK);
    k3_gemm<<<dim3(B/128, 21), 256, 0, stream>>>(coefT, PK, A_g, Q, out, B);
}